// Round 4
// baseline (272.127 us; speedup 1.0000x reference)
//
#include <hip/hip_runtime.h>
#include <math.h>

// NeuralstackOnly, 6-stage decomposition (R9: bisect R8's failure):
//  K1: g[b,t]   = elu(cos(latch_enable, x[b,t,:]))   wave-per-t, float4
//  K2: latch scan -> L[b,t,:]                         chunked load batching
//  K3: pop[b,t] = elu(cos(should_pop, L[b,t,:]))      wave-per-t, float4
//  K4: pointer recurrence -> P[b,t,32]                VERBATIM R7 (known good)
//  K4b: coef_kernel: P,pop -> C[b,t,32]={a,b,g,w}     trivially-parallel gather,
//       identical op sequence + identical stored-P inputs as R7's stack loop
//  K5: stack recurrence + readout                     consumes C, 3 FMA/slot/t
//
//  R8 post-mortem: fused coefficient emit inside ptr_scan + big CA[2][8]
//  staging failed correctness (absmax 1.68, garbage magnitudes). Layout and
//  algebra verified correct by inspection -> bisect: keep R7 ptr_scan, emit C
//  in a separate gather kernel whose semantics are checkable line-by-line,
//  simplify stack staging to named CA[8]/CB[8] (static indices, rule #20).
//  C aliases dead L region (stream-ordered); P at R7 offset (disjoint).
// B=128, T=256, D=256, NSTK=32.

#define NSTK 32
#define DDIM 256
#define ZO 1e-6f
#define EPSC 1e-8f
#define PEPS 1e-12f
#define MAXT 1024

__device__ __forceinline__ float elu_f(float c) {
    return (c > 0.f) ? c : expm1f(c);
}

// DPP cross-lane helpers (sum-reduce pairings within groups of 32) — verified R4
__device__ __forceinline__ float dpp_xor1(float x) {   // quad_perm [1,0,3,2]
    return __int_as_float(__builtin_amdgcn_update_dpp(0, __float_as_int(x), 0xB1, 0xF, 0xF, true));
}
__device__ __forceinline__ float dpp_xor2(float x) {   // quad_perm [2,3,0,1]
    return __int_as_float(__builtin_amdgcn_update_dpp(0, __float_as_int(x), 0x4E, 0xF, 0xF, true));
}
__device__ __forceinline__ float dpp_halfmirror(float x) {  // row_half_mirror
    return __int_as_float(__builtin_amdgcn_update_dpp(0, __float_as_int(x), 0x141, 0xF, 0xF, true));
}
__device__ __forceinline__ float dpp_mirror(float x) {      // row_mirror
    return __int_as_float(__builtin_amdgcn_update_dpp(0, __float_as_int(x), 0x140, 0xF, 0xF, true));
}
__device__ __forceinline__ float swz_xor16(float x) {  // lane ^= 16 within 32
    return __int_as_float(__builtin_amdgcn_ds_swizzle(__float_as_int(x), 0x401F));
}

// VALU cross-lane pair-sums via gfx950 permlane swaps (a=b=x -> a+b = x + x^k).
// Bit-identical summation order to acc += __shfl_xor(acc, k). Verified R7.
__device__ __forceinline__ float xor16_sum(float x) {
    float a = x, b = x;
    asm("v_permlane16_swap_b32 %0, %1" : "+v"(a), "+v"(b));
    return a + b;
}
__device__ __forceinline__ float xor32_sum(float x) {
    float a = x, b = x;
    asm("v_permlane32_swap_b32 %0, %1" : "+v"(a), "+v"(b));
    return a + b;
}

// ---------------- K1 / K3: wave-per-t cosine gate ---------------------------
__global__ void gate4_kernel(const float* __restrict__ vecs,   // [B,T,D]
                             const float* __restrict__ par,    // [D]
                             float* __restrict__ gout,         // [B,T]
                             int T) {
    const int b = blockIdx.y;
    const int t = blockIdx.x * 4 + (threadIdx.x >> 6);
    const int lane = threadIdx.x & 63;
    const float4 v = *(const float4*)(vecs + ((size_t)b * T + t) * DDIM + lane * 4);
    const float4 p = *(const float4*)(par + lane * 4);
    float r0 = v.x * p.x + v.y * p.y + v.z * p.z + v.w * p.w;
    float r1 = v.x * v.x + v.y * v.y + v.z * v.z + v.w * v.w;
    float r2 = p.x * p.x + p.y * p.y + p.z * p.z + p.w * p.w;
#pragma unroll
    for (int off = 32; off >= 1; off >>= 1) {
        r0 += __shfl_xor(r0, off, 64);
        r1 += __shfl_xor(r1, off, 64);
        r2 += __shfl_xor(r2, off, 64);
    }
    if (lane == 0) {
        const float c = r0 / (fmaxf(sqrtf(r2), EPSC) * fmaxf(sqrtf(r1), EPSC));
        gout[(size_t)b * T + t] = elu_f(c);
    }
}

// ---------------- K2: latch scan, chunked load batching ---------------------
__global__ void latch_scan_kernel(const float* __restrict__ x,       // [B,T,D]
                                  const float* __restrict__ latch0,  // [B,D]
                                  const float* __restrict__ g,       // [B,T]
                                  float* __restrict__ L,             // [B,T,D]
                                  int T) {
    const int b = blockIdx.x >> 2;
    const int dt = blockIdx.x & 3;
    const int d = dt * 64 + threadIdx.x;
    const float* xb = x + (size_t)b * T * DDIM + d;
    const float* gb = g + (size_t)b * T;
    float* Lb = L + (size_t)b * T * DDIM + d;
    float l = latch0[(size_t)b * DDIM + d];
    for (int c = 0; c < T; c += 32) {
        float xv[32], gv[32];
#pragma unroll
        for (int i = 0; i < 32; i++) xv[i] = xb[(size_t)(c + i) * DDIM];
#pragma unroll
        for (int i = 0; i < 32; i++) gv[i] = gb[c + i];
#pragma unroll
        for (int i = 0; i < 32; i++) {
            Lb[(size_t)(c + i) * DDIM] = l;           // latch ENTERING step c+i
            l = fmaf(gv[i], xv[i] - l, l);
        }
    }
}

// ---------------- K4: pointer recurrence, 2 b per wave (VERBATIM R7) --------
// Emits P[b,t,32] = normalized sharpened pointer AFTER step t (t=0..T-1).
__launch_bounds__(64, 1)
__global__ void ptr_scan_kernel(const float* __restrict__ pop_arr,  // [B,T]
                                const float* __restrict__ sharpen_ptr,
                                float* __restrict__ Parr,           // [B,T,32]
                                int T) {
    const int b0 = blockIdx.x * 2;
    const int tid = threadIdx.x;
    const int n = tid & 31;
    const int grp = tid >> 5;                  // 0/1 -> which b
    const float sharpen = sharpen_ptr[0];
    const bool sharp5 = (sharpen == 5.0f);

    __shared__ float pops[2 * MAXT];
    for (int i = tid; i < 2 * T; i += 64) pops[i] = pop_arr[(size_t)b0 * T + i];
    __syncthreads();
    const float* popg = pops + grp * T;
    float* Pb = Parr + (size_t)(b0 + grp) * T * 32;

    float u = (n == 0) ? 1.0f : ZO;    // unnormalized pointer entering step t
    float invu = 1.0f;                 // its normalizer (p = u * invu)
    int t = 0;

    auto step = [&](float pop) {
        const float push = 1.0f - pop;
        const float up = __shfl(u, (n + 31) & 31, 32);   // roll +1
        const float un = __shfl(u, (n + 1) & 31, 32);    // roll -1
        const float r = fmaf(push, up, pop * un);
        const float q = fmaxf(r * invu, PEPS);
        float unew;
        if (sharp5) { const float q2 = q * q, q4 = q2 * q2; unew = q4 * q; }
        else        { unew = exp2f(sharpen * log2f(q)); }
        float s = unew;
        s += dpp_xor1(s);
        s += dpp_xor2(s);
        s += dpp_halfmirror(s);
        s += dpp_mirror(s);
        s += swz_xor16(s);
        const float invn = 1.0f / fmaxf(s, EPSC);
        Pb[(size_t)t * 32 + n] = unew * invn;
        u = unew; invu = invn;
        t++;
    };

    const float4* p4 = (const float4*)popg;
    float4 cA0 = p4[0], cA1 = p4[1], cA2 = p4[2], cA3 = p4[3];
    for (int c = 0; c < T; c += 16) {
        float4 cB0, cB1, cB2, cB3;
        if (c + 16 < T) {
            const float4* pn4 = p4 + (c + 16) / 4;
            cB0 = pn4[0]; cB1 = pn4[1]; cB2 = pn4[2]; cB3 = pn4[3];
        }
        step(cA0.x); step(cA0.y); step(cA0.z); step(cA0.w);
        step(cA1.x); step(cA1.y); step(cA1.z); step(cA1.w);
        step(cA2.x); step(cA2.y); step(cA2.z); step(cA2.w);
        step(cA3.x); step(cA3.y); step(cA3.z); step(cA3.w);
        if (c + 16 < T) { cA0 = cB0; cA1 = cB1; cA2 = cB2; cA3 = cB3; }
    }
}

// ---------------- K4b: coefficient gather (R9, trivially parallel) ----------
// One lane per (t,n). Reads the SAME stored/rounded P values R7's stack read:
//   p  = P[t-1, n]            (pointer entering t; t=0 -> one-hot initial)
//   pp = P[t-1, (n+31)&31]    (slot n-1 with wrap; t=0 -> initial[n-1])
//   w  = P[t, n]              (pointer after t, readout weight)
// and applies R7's exact op sequence:
//   t0v = pop*p; m = fmaf(push,pp,t0v); alpha = 1-m; beta = push*pp; g2 = ZO*t0v.
__global__ void coef_kernel(const float* __restrict__ Parr,    // [B,T,32]
                            const float* __restrict__ pop_arr, // [B,T]
                            float* __restrict__ Carr,          // [B,T,32,4]
                            int T) {
    const int b = blockIdx.y;
    const int tid = threadIdx.x;
    const int t = blockIdx.x * 2 + (tid >> 5);
    const int n = tid & 31;
    const float* Pb = Parr + (size_t)b * T * 32;
    const float pop = pop_arr[(size_t)b * T + t];
    const float push = 1.0f - pop;
    float p, pp;
    if (t == 0) {
        p  = (n == 0) ? 1.0f : ZO;
        pp = (n == 1) ? 1.0f : ZO;
    } else {
        p  = Pb[(size_t)(t - 1) * 32 + n];
        pp = Pb[(size_t)(t - 1) * 32 + ((n + 31) & 31)];
    }
    const float w = Pb[(size_t)t * 32 + n];
    const float t0v = pop * p;
    const float m = fmaf(push, pp, t0v);
    const float alpha = 1.0f - m;
    const float beta = push * pp;
    const float g2 = ZO * t0v;
    float4 cv;
    cv.x = alpha; cv.y = beta; cv.z = g2; cv.w = w;
    ((float4*)Carr)[(size_t)b * T * 32 + (size_t)t * 32 + n] = cv;
}

// ---------------- K5: stack recurrence + readout (consumes C) ---------------
// Grid (D/16, B), single-wave blocks. Lane = 16 dsub x 4 ng (8 slots each).
// Per t: 8 dwordx4 C loads + 1 x + 1 pop; per slot exactly 3 FMA; VALU reduce.
// Named single-t buffers CA[8]/CB[8], prefetch distance 1 t, static indices.
#define SLOAD(CN, XV, POPV, tt) do {                                         \
    _Pragma("unroll") for (int k = 0; k < 8; k++)                            \
        CN[k] = Cb[(size_t)(tt) * 32 + k];                                   \
    XV = xb[(size_t)(tt) * DDIM];                                            \
    POPV = popb[(tt)];                                                       \
} while (0)

#define SSTEP(CN, XV, POPV, tt) do {                                         \
    float acc = 0.f;                                                         \
    _Pragma("unroll") for (int j = 0; j < 8; j++) {                          \
        const float4 c = CN[j];                                              \
        const float bxg = fmaf(c.y, XV, c.z);                                \
        const float ns = fmaf(c.x, st[j], bxg);                              \
        st[j] = ns;                                                          \
        acc = fmaf(c.w, ns, acc);                                            \
    }                                                                        \
    acc = xor16_sum(acc);                                                    \
    acc = xor32_sum(acc);                                                    \
    if (lane < 16) ob[(size_t)(tt) * DDIM] = POPV * acc;                     \
} while (0)

__launch_bounds__(64, 1)
__global__ void stack_kernel(const float* __restrict__ x,       // [B,T,D]
                             const float* __restrict__ Carr,    // [B,T,32,4]
                             const float* __restrict__ pop_arr, // [B,T]
                             float* __restrict__ out,           // [B,T,D]
                             int T) {
    const int b = blockIdx.y;
    const int dtile = blockIdx.x;              // 0..15
    const int lane = threadIdx.x;              // 0..63
    const int dsub = lane & 15;
    const int ng = lane >> 4;                  // slots ng*8..ng*8+7

    const float4* Cb = (const float4*)Carr + (size_t)b * T * 32 + ng * 8;
    const float* xb = x + (size_t)b * T * DDIM + dtile * 16 + dsub;
    const float* popb = pop_arr + (size_t)b * T;
    float* ob = out + (size_t)b * T * DDIM + dtile * 16 + dsub;

    float st[8];
#pragma unroll
    for (int j = 0; j < 8; j++) st[j] = ZO;

    float4 CA[8], CB[8];
    float xA, xB, popA, popB;

    SLOAD(CA, xA, popA, 0);
    for (int t = 0; t < T; t += 2) {
        SLOAD(CB, xB, popB, t + 1);            // T even: always valid
        SSTEP(CA, xA, popA, t);
        if (t + 2 < T) SLOAD(CA, xA, popA, t + 2);
        SSTEP(CB, xB, popB, t + 1);
    }
}

// ---------------- Fallback: monolithic kernel (correct, slower) -------------
__launch_bounds__(256, 1)
__global__ void neuralstack_kernel(const float* __restrict__ x,
                                   const float* __restrict__ should_pop,
                                   const float* __restrict__ sharpen_ptr,
                                   const float* __restrict__ latch_enable,
                                   const float* __restrict__ latch_init,
                                   float* __restrict__ out,
                                   int T) {
    const int b = blockIdx.x;
    const int tid = threadIdx.x;
    const int wave = tid >> 6;
    const int lane = tid & 63;
    __shared__ float red[2][16];
    const float sp_d = should_pop[tid];
    const float le_d = latch_enable[tid];
    const float sharpen = sharpen_ptr[0];
    float latch = latch_init[(size_t)b * DDIM + tid];
    float a0 = sp_d * sp_d, a1 = le_d * le_d;
#pragma unroll
    for (int off = 32; off >= 1; off >>= 1) {
        a0 += __shfl_xor(a0, off, 64);
        a1 += __shfl_xor(a1, off, 64);
    }
    if (lane == 0) { red[0][wave * 4] = a0; red[0][wave * 4 + 1] = a1; }
    __syncthreads();
    const float an_sp = fmaxf(sqrtf(red[0][0] + red[0][4] + red[0][8] + red[0][12]), EPSC);
    const float an_le = fmaxf(sqrtf(red[0][1] + red[0][5] + red[0][9] + red[0][13]), EPSC);
    __syncthreads();
    float st[NSTK], ptr[NSTK];
#pragma unroll
    for (int n = 0; n < NSTK; n++) { st[n] = ZO; ptr[n] = (n == 0) ? 1.0f : ZO; }
    const float* xb = x + (size_t)b * T * DDIM + tid;
    float* ob = out + (size_t)b * T * DDIM + tid;
    const bool sharp5 = (sharpen == 5.0f);
    float inp = xb[0];
    for (int t = 0; t < T; t++) {
        const int tn = (t + 1 < T) ? (t + 1) : (T - 1);
        const float inp_next = xb[(size_t)tn * DDIM];
        float r0 = sp_d * latch, r1 = latch * latch, r2 = le_d * inp, r3 = inp * inp;
#pragma unroll
        for (int off = 32; off >= 1; off >>= 1) {
            r0 += __shfl_xor(r0, off, 64);
            r1 += __shfl_xor(r1, off, 64);
            r2 += __shfl_xor(r2, off, 64);
            r3 += __shfl_xor(r3, off, 64);
        }
        const int buf = t & 1;
        if (lane == 0) {
            red[buf][wave * 4] = r0; red[buf][wave * 4 + 1] = r1;
            red[buf][wave * 4 + 2] = r2; red[buf][wave * 4 + 3] = r3;
        }
        __syncthreads();
        const float s0 = red[buf][0] + red[buf][4] + red[buf][8] + red[buf][12];
        const float s1 = red[buf][1] + red[buf][5] + red[buf][9] + red[buf][13];
        const float s2 = red[buf][2] + red[buf][6] + red[buf][10] + red[buf][14];
        const float s3 = red[buf][3] + red[buf][7] + red[buf][11] + red[buf][15];
        const float pop = elu_f(s0 / (an_sp * fmaxf(sqrtf(s1), EPSC)));
        const float push = 1.0f - pop;
        const float g = elu_f(s2 / (an_le * fmaxf(sqrtf(s3), EPSC)));
        float q[NSTK];
#pragma unroll
        for (int n = 0; n < NSTK; n++) {
            const float pp = ptr[(n + NSTK - 1) & (NSTK - 1)];
            const float pn = ptr[(n + 1) & (NSTK - 1)];
            q[n] = fmaxf(push * pp + pop * pn, PEPS);
        }
        if (sharp5) {
#pragma unroll
            for (int n = 0; n < NSTK; n++) { const float v = q[n], v2 = v * v; q[n] = v2 * v2 * v; }
        } else {
#pragma unroll
            for (int n = 0; n < NSTK; n++) q[n] = exp2f(sharpen * log2f(q[n]));
        }
        float qa = 0.f, qb = 0.f, qc = 0.f, qd = 0.f;
#pragma unroll
        for (int n = 0; n < NSTK; n += 4) { qa += q[n]; qb += q[n+1]; qc += q[n+2]; qd += q[n+3]; }
        const float inv = 1.0f / fmaxf((qa + qb) + (qc + qd), EPSC);
        float sacc = 0.f;
#pragma unroll
        for (int n = 0; n < NSTK; n++) {
            const float pp = ptr[(n + NSTK - 1) & (NSTK - 1)];
            const float pc_ = ptr[n];
            const float ns = push * (st[n] + pp * (inp - st[n])) + pop * (st[n] + pc_ * (ZO - st[n]));
            st[n] = ns;
            sacc += ns * (q[n] * inv);
        }
#pragma unroll
        for (int n = 0; n < NSTK; n++) ptr[n] = q[n] * inv;
        ob[(size_t)t * DDIM] = pop * sacc;
        latch = fmaf(g, inp - latch, latch);
        inp = inp_next;
    }
}

extern "C" void kernel_launch(void* const* d_in, const int* in_sizes, int n_in,
                              void* d_out, int out_size, void* d_ws, size_t ws_size,
                              hipStream_t stream) {
    const float* x = (const float*)d_in[0];
    const float* should_pop = (const float*)d_in[1];
    const float* sharpen_ptr = (const float*)d_in[2];
    const float* latch_enable = (const float*)d_in[3];
    const float* latch_init = (const float*)d_in[4];
    float* out = (float*)d_out;

    const int D = in_sizes[1];                 // 256
    const int B = in_sizes[4] / D;             // 128
    const int T = in_sizes[0] / in_sizes[4];   // 256
    (void)n_in; (void)out_size;

    const size_t BT = (size_t)B * T;
    const size_t off_g = 0;
    const size_t off_pop = BT;
    const size_t off_L = 2 * BT;               // L: [B,T,D]; C aliases first 128*BT of L
    const size_t off_P = off_L + BT * D;       // P: [B,T,32] (R7 offset, known to fit)
    const size_t need_floats = off_P + BT * 32;

    if (ws_size < need_floats * sizeof(float) || D != DDIM ||
        (T % 16) != 0 || (B % 2) != 0 || T > MAXT) {
        neuralstack_kernel<<<B, 256, 0, stream>>>(x, should_pop, sharpen_ptr,
                                                  latch_enable, latch_init, out, T);
        return;
    }

    float* ws = (float*)d_ws;
    float* g = ws + off_g;
    float* pop = ws + off_pop;
    float* L = ws + off_L;
    float* C = ws + off_L;                     // reuses dead L (stream-ordered)
    float* P = ws + off_P;

    gate4_kernel<<<dim3(T / 4, B), 256, 0, stream>>>(x, latch_enable, g, T);
    latch_scan_kernel<<<B * 4, 64, 0, stream>>>(x, latch_init, g, L, T);
    gate4_kernel<<<dim3(T / 4, B), 256, 0, stream>>>(L, should_pop, pop, T);
    ptr_scan_kernel<<<B / 2, 64, 0, stream>>>(pop, sharpen_ptr, P, T);
    coef_kernel<<<dim3(T / 2, B), 64, 0, stream>>>(P, pop, C, T);
    stack_kernel<<<dim3(D / 16, B), 64, 0, stream>>>(x, C, pop, out, T);
}

// Round 5
// 240.652 us; speedup vs baseline: 1.1308x; 1.1308x over previous
//
#include <hip/hip_runtime.h>
#include <math.h>

// NeuralstackOnly, 6-stage decomposition (R10: stack geometry Dl=4, dist-2):
//  K1: g[b,t]   = elu(cos(latch_enable, x[b,t,:]))   wave-per-t, float4
//  K2: latch scan -> L[b,t,:]                         chunked load batching
//  K3: pop[b,t] = elu(cos(should_pop, L[b,t,:]))      wave-per-t, float4
//  K4: pointer recurrence -> P[b,t,32]                VERBATIM R7 (known good)
//  K4b: coef gather: P,pop -> C[b,t,32]={a,b,g,w}     VERBATIM R9 (known good)
//  K5: stack recurrence + readout                     R10: 4 d per lane
//
//  R9 post-mortem: C-consumption correct but latency-bound (VALU 31%, HBM 13%,
//  occ 22%): ~95 instr/wave-t of which only 24 useful FMA (512 cells), and
//  dist-1 prefetch (~190 cy cover) < C-load L2/L3 latency (~300-600 cy).
//  R10: lane = 16 dsub x 4 ng, each lane 8 slots x 4 CONTIGUOUS d ->
//  2048 cells/wave-t, 96 FMA + 8 C-loads + dwordx4 x/out, ~75% useful issue,
//  grid (D/64, B) = 512 waves. Prefetch distance 2 (A0/A1/B0/B1 named bufs,
//  all static indices). Per-d slot-partial order unchanged -> bit-identical.
// B=128, T=256, D=256, NSTK=32.

#define NSTK 32
#define DDIM 256
#define ZO 1e-6f
#define EPSC 1e-8f
#define PEPS 1e-12f
#define MAXT 1024

__device__ __forceinline__ float elu_f(float c) {
    return (c > 0.f) ? c : expm1f(c);
}

// DPP cross-lane helpers (sum-reduce pairings within groups of 32) — verified R4
__device__ __forceinline__ float dpp_xor1(float x) {   // quad_perm [1,0,3,2]
    return __int_as_float(__builtin_amdgcn_update_dpp(0, __float_as_int(x), 0xB1, 0xF, 0xF, true));
}
__device__ __forceinline__ float dpp_xor2(float x) {   // quad_perm [2,3,0,1]
    return __int_as_float(__builtin_amdgcn_update_dpp(0, __float_as_int(x), 0x4E, 0xF, 0xF, true));
}
__device__ __forceinline__ float dpp_halfmirror(float x) {  // row_half_mirror
    return __int_as_float(__builtin_amdgcn_update_dpp(0, __float_as_int(x), 0x141, 0xF, 0xF, true));
}
__device__ __forceinline__ float dpp_mirror(float x) {      // row_mirror
    return __int_as_float(__builtin_amdgcn_update_dpp(0, __float_as_int(x), 0x140, 0xF, 0xF, true));
}
__device__ __forceinline__ float swz_xor16(float x) {  // lane ^= 16 within 32
    return __int_as_float(__builtin_amdgcn_ds_swizzle(__float_as_int(x), 0x401F));
}

// VALU cross-lane pair-sums via gfx950 permlane swaps (a=b=x -> a+b = x + x^k).
// Bit-identical summation order to acc += __shfl_xor(acc, k). Verified R7-R9.
__device__ __forceinline__ float xor16_sum(float x) {
    float a = x, b = x;
    asm("v_permlane16_swap_b32 %0, %1" : "+v"(a), "+v"(b));
    return a + b;
}
__device__ __forceinline__ float xor32_sum(float x) {
    float a = x, b = x;
    asm("v_permlane32_swap_b32 %0, %1" : "+v"(a), "+v"(b));
    return a + b;
}

// ---------------- K1 / K3: wave-per-t cosine gate ---------------------------
__global__ void gate4_kernel(const float* __restrict__ vecs,   // [B,T,D]
                             const float* __restrict__ par,    // [D]
                             float* __restrict__ gout,         // [B,T]
                             int T) {
    const int b = blockIdx.y;
    const int t = blockIdx.x * 4 + (threadIdx.x >> 6);
    const int lane = threadIdx.x & 63;
    const float4 v = *(const float4*)(vecs + ((size_t)b * T + t) * DDIM + lane * 4);
    const float4 p = *(const float4*)(par + lane * 4);
    float r0 = v.x * p.x + v.y * p.y + v.z * p.z + v.w * p.w;
    float r1 = v.x * v.x + v.y * v.y + v.z * v.z + v.w * v.w;
    float r2 = p.x * p.x + p.y * p.y + p.z * p.z + p.w * p.w;
#pragma unroll
    for (int off = 32; off >= 1; off >>= 1) {
        r0 += __shfl_xor(r0, off, 64);
        r1 += __shfl_xor(r1, off, 64);
        r2 += __shfl_xor(r2, off, 64);
    }
    if (lane == 0) {
        const float c = r0 / (fmaxf(sqrtf(r2), EPSC) * fmaxf(sqrtf(r1), EPSC));
        gout[(size_t)b * T + t] = elu_f(c);
    }
}

// ---------------- K2: latch scan, chunked load batching ---------------------
__global__ void latch_scan_kernel(const float* __restrict__ x,       // [B,T,D]
                                  const float* __restrict__ latch0,  // [B,D]
                                  const float* __restrict__ g,       // [B,T]
                                  float* __restrict__ L,             // [B,T,D]
                                  int T) {
    const int b = blockIdx.x >> 2;
    const int dt = blockIdx.x & 3;
    const int d = dt * 64 + threadIdx.x;
    const float* xb = x + (size_t)b * T * DDIM + d;
    const float* gb = g + (size_t)b * T;
    float* Lb = L + (size_t)b * T * DDIM + d;
    float l = latch0[(size_t)b * DDIM + d];
    for (int c = 0; c < T; c += 32) {
        float xv[32], gv[32];
#pragma unroll
        for (int i = 0; i < 32; i++) xv[i] = xb[(size_t)(c + i) * DDIM];
#pragma unroll
        for (int i = 0; i < 32; i++) gv[i] = gb[c + i];
#pragma unroll
        for (int i = 0; i < 32; i++) {
            Lb[(size_t)(c + i) * DDIM] = l;           // latch ENTERING step c+i
            l = fmaf(gv[i], xv[i] - l, l);
        }
    }
}

// ---------------- K4: pointer recurrence, 2 b per wave (VERBATIM R7) --------
// Emits P[b,t,32] = normalized sharpened pointer AFTER step t (t=0..T-1).
__launch_bounds__(64, 1)
__global__ void ptr_scan_kernel(const float* __restrict__ pop_arr,  // [B,T]
                                const float* __restrict__ sharpen_ptr,
                                float* __restrict__ Parr,           // [B,T,32]
                                int T) {
    const int b0 = blockIdx.x * 2;
    const int tid = threadIdx.x;
    const int n = tid & 31;
    const int grp = tid >> 5;                  // 0/1 -> which b
    const float sharpen = sharpen_ptr[0];
    const bool sharp5 = (sharpen == 5.0f);

    __shared__ float pops[2 * MAXT];
    for (int i = tid; i < 2 * T; i += 64) pops[i] = pop_arr[(size_t)b0 * T + i];
    __syncthreads();
    const float* popg = pops + grp * T;
    float* Pb = Parr + (size_t)(b0 + grp) * T * 32;

    float u = (n == 0) ? 1.0f : ZO;    // unnormalized pointer entering step t
    float invu = 1.0f;                 // its normalizer (p = u * invu)
    int t = 0;

    auto step = [&](float pop) {
        const float push = 1.0f - pop;
        const float up = __shfl(u, (n + 31) & 31, 32);   // roll +1
        const float un = __shfl(u, (n + 1) & 31, 32);    // roll -1
        const float r = fmaf(push, up, pop * un);
        const float q = fmaxf(r * invu, PEPS);
        float unew;
        if (sharp5) { const float q2 = q * q, q4 = q2 * q2; unew = q4 * q; }
        else        { unew = exp2f(sharpen * log2f(q)); }
        float s = unew;
        s += dpp_xor1(s);
        s += dpp_xor2(s);
        s += dpp_halfmirror(s);
        s += dpp_mirror(s);
        s += swz_xor16(s);
        const float invn = 1.0f / fmaxf(s, EPSC);
        Pb[(size_t)t * 32 + n] = unew * invn;
        u = unew; invu = invn;
        t++;
    };

    const float4* p4 = (const float4*)popg;
    float4 cA0 = p4[0], cA1 = p4[1], cA2 = p4[2], cA3 = p4[3];
    for (int c = 0; c < T; c += 16) {
        float4 cB0, cB1, cB2, cB3;
        if (c + 16 < T) {
            const float4* pn4 = p4 + (c + 16) / 4;
            cB0 = pn4[0]; cB1 = pn4[1]; cB2 = pn4[2]; cB3 = pn4[3];
        }
        step(cA0.x); step(cA0.y); step(cA0.z); step(cA0.w);
        step(cA1.x); step(cA1.y); step(cA1.z); step(cA1.w);
        step(cA2.x); step(cA2.y); step(cA2.z); step(cA2.w);
        step(cA3.x); step(cA3.y); step(cA3.z); step(cA3.w);
        if (c + 16 < T) { cA0 = cB0; cA1 = cB1; cA2 = cB2; cA3 = cB3; }
    }
}

// ---------------- K4b: coefficient gather (VERBATIM R9, known good) ---------
__global__ void coef_kernel(const float* __restrict__ Parr,    // [B,T,32]
                            const float* __restrict__ pop_arr, // [B,T]
                            float* __restrict__ Carr,          // [B,T,32,4]
                            int T) {
    const int b = blockIdx.y;
    const int tid = threadIdx.x;
    const int t = blockIdx.x * 2 + (tid >> 5);
    const int n = tid & 31;
    const float* Pb = Parr + (size_t)b * T * 32;
    const float pop = pop_arr[(size_t)b * T + t];
    const float push = 1.0f - pop;
    float p, pp;
    if (t == 0) {
        p  = (n == 0) ? 1.0f : ZO;
        pp = (n == 1) ? 1.0f : ZO;
    } else {
        p  = Pb[(size_t)(t - 1) * 32 + n];
        pp = Pb[(size_t)(t - 1) * 32 + ((n + 31) & 31)];
    }
    const float w = Pb[(size_t)t * 32 + n];
    const float t0v = pop * p;
    const float m = fmaf(push, pp, t0v);
    const float alpha = 1.0f - m;
    const float beta = push * pp;
    const float g2 = ZO * t0v;
    float4 cv;
    cv.x = alpha; cv.y = beta; cv.z = g2; cv.w = w;
    ((float4*)Carr)[(size_t)b * T * 32 + (size_t)t * 32 + n] = cv;
}

// ---------------- K5: stack recurrence + readout (R10: Dl=4, dist-2) --------
// Grid (D/64, B), single-wave blocks. Lane = 16 dsub x 4 ng; each lane owns
// 8 slots x 4 contiguous d (d = dtile*64 + dsub*4 + 0..3).
// Per t: 8 dwordx4 C loads + 1 dwordx4 x + 1 pop; 96 FMA; 2-stage permlane
// reduce per d; ng==0 lanes store dwordx4. Prefetch distance 2 t.
#define SLOAD10(CN, XV, POPV, tt) do {                                       \
    const float4* _cp = Cb + (size_t)(tt) * 32;                              \
    _Pragma("unroll") for (int k = 0; k < 8; k++) CN[k] = _cp[k];            \
    XV = *(const float4*)(xb + (size_t)(tt) * DDIM);                         \
    POPV = popb[(tt)];                                                       \
} while (0)

#define SSTEP10(CN, XV, POPV, tt) do {                                       \
    float a0 = 0.f, a1 = 0.f, a2 = 0.f, a3 = 0.f;                            \
    _Pragma("unroll") for (int j = 0; j < 8; j++) {                          \
        const float4 c = CN[j];                                              \
        const float b0 = fmaf(c.y, XV.x, c.z);                               \
        const float b1 = fmaf(c.y, XV.y, c.z);                               \
        const float b2 = fmaf(c.y, XV.z, c.z);                               \
        const float b3 = fmaf(c.y, XV.w, c.z);                               \
        const float n0 = fmaf(c.x, st[j][0], b0);                            \
        const float n1 = fmaf(c.x, st[j][1], b1);                            \
        const float n2 = fmaf(c.x, st[j][2], b2);                            \
        const float n3 = fmaf(c.x, st[j][3], b3);                            \
        st[j][0] = n0; st[j][1] = n1; st[j][2] = n2; st[j][3] = n3;          \
        a0 = fmaf(c.w, n0, a0);                                              \
        a1 = fmaf(c.w, n1, a1);                                              \
        a2 = fmaf(c.w, n2, a2);                                              \
        a3 = fmaf(c.w, n3, a3);                                              \
    }                                                                        \
    a0 = xor16_sum(a0); a0 = xor32_sum(a0);                                  \
    a1 = xor16_sum(a1); a1 = xor32_sum(a1);                                  \
    a2 = xor16_sum(a2); a2 = xor32_sum(a2);                                  \
    a3 = xor16_sum(a3); a3 = xor32_sum(a3);                                  \
    if (lane < 16) {                                                         \
        float4 o;                                                            \
        o.x = POPV * a0; o.y = POPV * a1; o.z = POPV * a2; o.w = POPV * a3;  \
        *(float4*)(ob + (size_t)(tt) * DDIM) = o;                            \
    }                                                                        \
} while (0)

__launch_bounds__(64, 1)
__global__ void stack_kernel(const float* __restrict__ x,       // [B,T,D]
                             const float* __restrict__ Carr,    // [B,T,32,4]
                             const float* __restrict__ pop_arr, // [B,T]
                             float* __restrict__ out,           // [B,T,D]
                             int T) {
    const int b = blockIdx.y;
    const int dtile = blockIdx.x;              // 0..D/64-1
    const int lane = threadIdx.x;              // 0..63
    const int dsub = lane & 15;                // d-group of 4
    const int ng = lane >> 4;                  // slots ng*8..ng*8+7

    const float4* Cb = (const float4*)Carr + (size_t)b * T * 32 + ng * 8;
    const float* xb = x + (size_t)b * T * DDIM + dtile * 64 + dsub * 4;
    const float* popb = pop_arr + (size_t)b * T;
    float* ob = out + (size_t)b * T * DDIM + dtile * 64 + dsub * 4;

    float st[8][4];
#pragma unroll
    for (int j = 0; j < 8; j++) {
        st[j][0] = ZO; st[j][1] = ZO; st[j][2] = ZO; st[j][3] = ZO;
    }

    float4 CA0[8], CA1[8], CB0[8], CB1[8];
    float4 xA0, xA1, xB0, xB1;
    float popA0, popA1, popB0, popB1;

    SLOAD10(CA0, xA0, popA0, 0);
    SLOAD10(CA1, xA1, popA1, 1);
    for (int t = 0; t < T; t += 4) {
        SLOAD10(CB0, xB0, popB0, t + 2);       // always < T (T % 4 == 0)
        SLOAD10(CB1, xB1, popB1, t + 3);
        SSTEP10(CA0, xA0, popA0, t);
        SSTEP10(CA1, xA1, popA1, t + 1);
        if (t + 4 < T) SLOAD10(CA0, xA0, popA0, t + 4);
        if (t + 5 < T) SLOAD10(CA1, xA1, popA1, t + 5);
        SSTEP10(CB0, xB0, popB0, t + 2);
        SSTEP10(CB1, xB1, popB1, t + 3);
    }
}

// ---------------- Fallback: monolithic kernel (correct, slower) -------------
__launch_bounds__(256, 1)
__global__ void neuralstack_kernel(const float* __restrict__ x,
                                   const float* __restrict__ should_pop,
                                   const float* __restrict__ sharpen_ptr,
                                   const float* __restrict__ latch_enable,
                                   const float* __restrict__ latch_init,
                                   float* __restrict__ out,
                                   int T) {
    const int b = blockIdx.x;
    const int tid = threadIdx.x;
    const int wave = tid >> 6;
    const int lane = tid & 63;
    __shared__ float red[2][16];
    const float sp_d = should_pop[tid];
    const float le_d = latch_enable[tid];
    const float sharpen = sharpen_ptr[0];
    float latch = latch_init[(size_t)b * DDIM + tid];
    float a0 = sp_d * sp_d, a1 = le_d * le_d;
#pragma unroll
    for (int off = 32; off >= 1; off >>= 1) {
        a0 += __shfl_xor(a0, off, 64);
        a1 += __shfl_xor(a1, off, 64);
    }
    if (lane == 0) { red[0][wave * 4] = a0; red[0][wave * 4 + 1] = a1; }
    __syncthreads();
    const float an_sp = fmaxf(sqrtf(red[0][0] + red[0][4] + red[0][8] + red[0][12]), EPSC);
    const float an_le = fmaxf(sqrtf(red[0][1] + red[0][5] + red[0][9] + red[0][13]), EPSC);
    __syncthreads();
    float st[NSTK], ptr[NSTK];
#pragma unroll
    for (int n = 0; n < NSTK; n++) { st[n] = ZO; ptr[n] = (n == 0) ? 1.0f : ZO; }
    const float* xb = x + (size_t)b * T * DDIM + tid;
    float* ob = out + (size_t)b * T * DDIM + tid;
    const bool sharp5 = (sharpen == 5.0f);
    float inp = xb[0];
    for (int t = 0; t < T; t++) {
        const int tn = (t + 1 < T) ? (t + 1) : (T - 1);
        const float inp_next = xb[(size_t)tn * DDIM];
        float r0 = sp_d * latch, r1 = latch * latch, r2 = le_d * inp, r3 = inp * inp;
#pragma unroll
        for (int off = 32; off >= 1; off >>= 1) {
            r0 += __shfl_xor(r0, off, 64);
            r1 += __shfl_xor(r1, off, 64);
            r2 += __shfl_xor(r2, off, 64);
            r3 += __shfl_xor(r3, off, 64);
        }
        const int buf = t & 1;
        if (lane == 0) {
            red[buf][wave * 4] = r0; red[buf][wave * 4 + 1] = r1;
            red[buf][wave * 4 + 2] = r2; red[buf][wave * 4 + 3] = r3;
        }
        __syncthreads();
        const float s0 = red[buf][0] + red[buf][4] + red[buf][8] + red[buf][12];
        const float s1 = red[buf][1] + red[buf][5] + red[buf][9] + red[buf][13];
        const float s2 = red[buf][2] + red[buf][6] + red[buf][10] + red[buf][14];
        const float s3 = red[buf][3] + red[buf][7] + red[buf][11] + red[buf][15];
        const float pop = elu_f(s0 / (an_sp * fmaxf(sqrtf(s1), EPSC)));
        const float push = 1.0f - pop;
        const float g = elu_f(s2 / (an_le * fmaxf(sqrtf(s3), EPSC)));
        float q[NSTK];
#pragma unroll
        for (int n = 0; n < NSTK; n++) {
            const float pp = ptr[(n + NSTK - 1) & (NSTK - 1)];
            const float pn = ptr[(n + 1) & (NSTK - 1)];
            q[n] = fmaxf(push * pp + pop * pn, PEPS);
        }
        if (sharp5) {
#pragma unroll
            for (int n = 0; n < NSTK; n++) { const float v = q[n], v2 = v * v; q[n] = v2 * v2 * v; }
        } else {
#pragma unroll
            for (int n = 0; n < NSTK; n++) q[n] = exp2f(sharpen * log2f(q[n]));
        }
        float qa = 0.f, qb = 0.f, qc = 0.f, qd = 0.f;
#pragma unroll
        for (int n = 0; n < NSTK; n += 4) { qa += q[n]; qb += q[n+1]; qc += q[n+2]; qd += q[n+3]; }
        const float inv = 1.0f / fmaxf((qa + qb) + (qc + qd), EPSC);
        float sacc = 0.f;
#pragma unroll
        for (int n = 0; n < NSTK; n++) {
            const float pp = ptr[(n + NSTK - 1) & (NSTK - 1)];
            const float pc_ = ptr[n];
            const float ns = push * (st[n] + pp * (inp - st[n])) + pop * (st[n] + pc_ * (ZO - st[n]));
            st[n] = ns;
            sacc += ns * (q[n] * inv);
        }
#pragma unroll
        for (int n = 0; n < NSTK; n++) ptr[n] = q[n] * inv;
        ob[(size_t)t * DDIM] = pop * sacc;
        latch = fmaf(g, inp - latch, latch);
        inp = inp_next;
    }
}

extern "C" void kernel_launch(void* const* d_in, const int* in_sizes, int n_in,
                              void* d_out, int out_size, void* d_ws, size_t ws_size,
                              hipStream_t stream) {
    const float* x = (const float*)d_in[0];
    const float* should_pop = (const float*)d_in[1];
    const float* sharpen_ptr = (const float*)d_in[2];
    const float* latch_enable = (const float*)d_in[3];
    const float* latch_init = (const float*)d_in[4];
    float* out = (float*)d_out;

    const int D = in_sizes[1];                 // 256
    const int B = in_sizes[4] / D;             // 128
    const int T = in_sizes[0] / in_sizes[4];   // 256
    (void)n_in; (void)out_size;

    const size_t BT = (size_t)B * T;
    const size_t off_g = 0;
    const size_t off_pop = BT;
    const size_t off_L = 2 * BT;               // L: [B,T,D]; C aliases first 128*BT of L
    const size_t off_P = off_L + BT * D;       // P: [B,T,32]
    const size_t need_floats = off_P + BT * 32;

    if (ws_size < need_floats * sizeof(float) || D != DDIM ||
        (T % 16) != 0 || (B % 2) != 0 || T > MAXT) {
        neuralstack_kernel<<<B, 256, 0, stream>>>(x, should_pop, sharpen_ptr,
                                                  latch_enable, latch_init, out, T);
        return;
    }

    float* ws = (float*)d_ws;
    float* g = ws + off_g;
    float* pop = ws + off_pop;
    float* L = ws + off_L;
    float* C = ws + off_L;                     // reuses dead L (stream-ordered)
    float* P = ws + off_P;

    gate4_kernel<<<dim3(T / 4, B), 256, 0, stream>>>(x, latch_enable, g, T);
    latch_scan_kernel<<<B * 4, 64, 0, stream>>>(x, latch_init, g, L, T);
    gate4_kernel<<<dim3(T / 4, B), 256, 0, stream>>>(L, should_pop, pop, T);
    ptr_scan_kernel<<<B / 2, 64, 0, stream>>>(pop, sharpen_ptr, P, T);
    coef_kernel<<<dim3(T / 2, B), 64, 0, stream>>>(P, pop, C, T);
    stack_kernel<<<dim3(D / 64, B), 64, 0, stream>>>(x, C, pop, out, T);
}